// Round 3
// baseline (14914.278 us; speedup 1.0000x reference)
//
#include <hip/hip_runtime.h>
#include <hip/hip_bf16.h>

// Sizes (fixed by the problem)
#define B_   64
#define T_   512
#define I_   512
#define H_   512
#define NBLK 64    // 32 blocks per layer; block owns 16 hidden units (64 gate cols)
#define NTHR 512   // 8 waves; wave = (mtile = w&3) x (unit-half = w>>2)

typedef short bf16x8 __attribute__((ext_vector_type(8)));
typedef float f32x4  __attribute__((ext_vector_type(4)));
typedef unsigned long long u64;
typedef unsigned short u16;

__device__ __forceinline__ u16 f2b(float f) {
    __hip_bfloat16 h = __float2bfloat16(f);   // RNE
    return __builtin_bit_cast(u16, h);
}

// Agent-scope (device-coherent, LLC-backed) 16B load from two u64 relaxed atomics.
__device__ __forceinline__ bf16x8 coh_ld8(const u16* p) {
    u64 lo = __hip_atomic_load((const u64*)p,     __ATOMIC_RELAXED, __HIP_MEMORY_SCOPE_AGENT);
    u64 hi = __hip_atomic_load((const u64*)p + 1, __ATOMIC_RELAXED, __HIP_MEMORY_SCOPE_AGENT);
    union { u64 q[2]; bf16x8 v; } u;
    u.q[0] = lo; u.q[1] = hi;
    return u.v;
}

// lane i checks 4 flags (16B) of flag-group i; true if all >= tgt. 256 flags total.
__device__ __forceinline__ bool flags_ge(const int* f, int lane, int tgt) {
    const u64* p = (const u64*)(f + 4 * lane);
    u64 a = __hip_atomic_load(p,     __ATOMIC_RELAXED, __HIP_MEMORY_SCOPE_AGENT);
    u64 b = __hip_atomic_load(p + 1, __ATOMIC_RELAXED, __HIP_MEMORY_SCOPE_AGENT);
    int m0 = min((int)(unsigned)a, (int)(a >> 32));
    int m1 = min((int)(unsigned)b, (int)(b >> 32));
    return min(m0, m1) >= tgt;
}

__device__ __forceinline__ float sigm(float z) { return 1.f / (1.f + __expf(-z)); }
__device__ __forceinline__ float tanhfast(float z) { return 1.f - 2.f / (__expf(2.f * z) + 1.f); }

// Init: x fp32 -> bf16, initial h -> ring slot 7 (both layers), flags = 0.
__global__ void k_init(const float* __restrict__ x, const float* __restrict__ h,
                       u16* __restrict__ xb, u16* __restrict__ h0ring, u16* __restrict__ h1ring,
                       int* __restrict__ flags0, int* __restrict__ flags1) {
    long i = (long)blockIdx.x * 256 + threadIdx.x;
    if (i < 2097152) {                          // x: 16,777,216 floats, 8 per thread
        const float* p = x + i * 8;
        float4 a = *(const float4*)p;
        float4 b = *(const float4*)(p + 4);
        union { u16 s[8]; bf16x8 v; } u;
        u.s[0]=f2b(a.x); u.s[1]=f2b(a.y); u.s[2]=f2b(a.z); u.s[3]=f2b(a.w);
        u.s[4]=f2b(b.x); u.s[5]=f2b(b.y); u.s[6]=f2b(b.z); u.s[7]=f2b(b.w);
        *(bf16x8*)(xb + i * 8) = u.v;
    } else if (i < 2097152 + 8192) {            // h: [2][64][512] = 65536 floats
        long j = i - 2097152;
        const float* p = h + j * 8;
        #pragma unroll
        for (int jj = 0; jj < 8; ++jj) {
            long idx = j * 8 + jj;
            u16 v = f2b(p[jj]);
            if (idx < 32768) h0ring[7 * 32768 + idx] = v;
            else             h1ring[7 * 32768 + (idx - 32768)] = v;
        }
    } else if (i < 2097152 + 8192 + 512) {      // flags
        int j = (int)(i - (2097152 + 8192));
        if (j < 256) flags0[j] = 0; else flags1[j - 256] = 0;
    }
}

__global__ __launch_bounds__(NTHR, 1) void k_lstm(
    const u16* __restrict__ xb,
    const float* __restrict__ Wx0, const float* __restrict__ Wh0, const float* __restrict__ b0,
    const float* __restrict__ Wx1, const float* __restrict__ Wh1, const float* __restrict__ b1,
    const float* __restrict__ c_in,
    u16* __restrict__ h0ring, u16* __restrict__ h1ring,
    int* __restrict__ flags0, int* __restrict__ flags1,
    float* __restrict__ out)
{
    __shared__ u16   stage_h[8][16][8];   // per wave: 16 rows x 8 units (bf16)
    __shared__ float stage_o[8][16][8];   // per wave: 16 rows x 8 units (fp32, layer1 out)

    const int tid  = threadIdx.x;
    const int bid  = blockIdx.x;
    const int lay  = bid >> 5;        // 0 or 1
    const int ub   = bid & 31;        // block owns units [ub*16, ub*16+16)
    const int w    = tid >> 6;        // wave 0..7
    const int lane = tid & 63;
    const int n    = lane & 15;       // A row-in-tile / B col-in-tile
    const int quad = lane >> 4;
    const int mt   = w & 3;           // M-tile (rows [16*mt, 16*mt+16))
    const int ug8  = ub * 2 + (w >> 2); // 8-unit group 0..63 this wave owns

    const float* Wx = lay ? Wx1 : Wx0;
    const float* Wh = lay ? Wh1 : Wh0;
    const float* bb = lay ? b1  : b0;
    const float bi = bb[0] + bb[1];
    const float bf = bb[2] + bb[3];
    const float bg = bb[4] + bb[5];
    const float bo = bb[6] + bb[7];

    // ---- Preload this wave's weight B-fragments into registers (once). ----
    // breg[ct][f]: col-tile ct (32 gate-cols of this wave's 8-unit group),
    // K-window f*32..+32 (K=[0,512): Wx, [512,1024): Wh).
    // B-frag: lane holds B[k = quad*8 + j][col = ct*16 + n].
    bf16x8 breg[2][32];
    #pragma unroll
    for (int ct = 0; ct < 2; ++ct) {
        const int c    = ct * 16 + n;
        const int gcol = (c >> 3) * 512 + ug8 * 8 + (c & 7); // global gate column
        #pragma unroll
        for (int f = 0; f < 32; ++f) {
            const int kbase = f * 32 + quad * 8;
            bf16x8 wv;
            #pragma unroll
            for (int j = 0; j < 8; ++j) {
                const int k = kbase + j;
                const float v = (k < 512) ? Wx[(size_t)k * 2048 + gcol]
                                          : Wh[(size_t)(k - 512) * 2048 + gcol];
                wv[j] = (short)f2b(v);
            }
            breg[ct][f] = wv;
        }
    }

    const int mrow0 = mt * 16;
    const int arow  = mrow0 + n;            // A row this lane supplies
    int* myflag = (lay ? flags1 : flags0) + ub * 8 + w;

    // c-state lives in registers (active lanes n<8 own rows mrow0+quad*4+r, unit ug8*8+n)
    float creg[4];
    if (n < 8) {
        const int ug = ug8 * 8 + n;
        #pragma unroll
        for (int r = 0; r < 4; ++r)
            creg[r] = c_in[(size_t)lay * 32768 + (mrow0 + quad * 4 + r) * 512 + ug];
    }

    for (int t = 0; t < 512; ++t) {
        f32x4 acc0 = {0.f, 0.f, 0.f, 0.f};
        f32x4 acc1 = {0.f, 0.f, 0.f, 0.f};

        if (lay == 0) {
            // prefetch x fragments before the poll (independent of h)
            const u16* px = xb + ((size_t)arow * T_ + t) * I_;
            bf16x8 xa[16];
            #pragma unroll
            for (int f = 0; f < 16; ++f)
                xa[f] = *(const bf16x8*)(px + f * 32 + quad * 8);

            // wait: peers done t-1 (h0[t-1] ready); layer1 done t-6 (ring WAR)
            while (!__all(flags_ge(flags0, lane, t) && flags_ge(flags1, lane, t - 6)))
                __builtin_amdgcn_s_sleep(1);
            asm volatile("" ::: "memory");

            const u16* ph = h0ring + ((t - 1) & 7) * 32768 + arow * H_;
            bf16x8 ha[16];
            #pragma unroll
            for (int f = 0; f < 16; ++f)
                ha[f] = coh_ld8(ph + f * 32 + quad * 8);

            #pragma unroll
            for (int f = 0; f < 16; ++f) {
                acc0 = __builtin_amdgcn_mfma_f32_16x16x32_bf16(xa[f], breg[0][f], acc0, 0, 0, 0);
                acc1 = __builtin_amdgcn_mfma_f32_16x16x32_bf16(xa[f], breg[1][f], acc1, 0, 0, 0);
            }
            #pragma unroll
            for (int f = 0; f < 16; ++f) {
                acc0 = __builtin_amdgcn_mfma_f32_16x16x32_bf16(ha[f], breg[0][16 + f], acc0, 0, 0, 0);
                acc1 = __builtin_amdgcn_mfma_f32_16x16x32_bf16(ha[f], breg[1][16 + f], acc1, 0, 0, 0);
            }
        } else {
            // phase 1: own-layer h1[t-1]
            while (!__all(flags_ge(flags1, lane, t)))
                __builtin_amdgcn_s_sleep(1);
            asm volatile("" ::: "memory");
            const u16* p1 = h1ring + ((t - 1) & 7) * 32768 + arow * H_;
            bf16x8 ha1[16];
            #pragma unroll
            for (int f = 0; f < 16; ++f)
                ha1[f] = coh_ld8(p1 + f * 32 + quad * 8);

            // phase 2: layer0's h0[t]
            while (!__all(flags_ge(flags0, lane, t + 1)))
                __builtin_amdgcn_s_sleep(1);
            asm volatile("" ::: "memory");
            const u16* p0 = h0ring + (t & 7) * 32768 + arow * H_;
            bf16x8 ha0[16];
            #pragma unroll
            for (int f = 0; f < 16; ++f)
                ha0[f] = coh_ld8(p0 + f * 32 + quad * 8);

            #pragma unroll
            for (int f = 0; f < 16; ++f) {
                acc0 = __builtin_amdgcn_mfma_f32_16x16x32_bf16(ha1[f], breg[0][16 + f], acc0, 0, 0, 0);
                acc1 = __builtin_amdgcn_mfma_f32_16x16x32_bf16(ha1[f], breg[1][16 + f], acc1, 0, 0, 0);
            }
            #pragma unroll
            for (int f = 0; f < 16; ++f) {
                acc0 = __builtin_amdgcn_mfma_f32_16x16x32_bf16(ha0[f], breg[0][f], acc0, 0, 0, 0);
                acc1 = __builtin_amdgcn_mfma_f32_16x16x32_bf16(ha0[f], breg[1][f], acc1, 0, 0, 0);
            }
        }

        // D layout: col = lane&15, row = quad*4 + reg.
        // acc0 cols: n<8 -> gate i (unit n), n>=8 -> gate f (unit n-8)
        // acc1 cols: n<8 -> gate g,          n>=8 -> gate o
        f32x4 s0, s1;
        #pragma unroll
        for (int r = 0; r < 4; ++r) {
            s0[r] = __shfl_xor(acc0[r], 8);   // lane n gets zf
            s1[r] = __shfl_xor(acc1[r], 8);   // lane n gets zo
        }
        if (n < 8) {
            const int ug = ug8 * 8 + n;
            #pragma unroll
            for (int r = 0; r < 4; ++r) {
                const int row = mrow0 + quad * 4 + r;
                const float zi = acc0[r] + bi;
                const float zf = s0[r]   + bf;
                const float zg = acc1[r] + bg;
                const float zo = s1[r]   + bo;
                const float ig = sigm(zi);
                const float fg = sigm(zf);
                const float gg = tanhfast(zg);
                const float og = sigm(zo);
                const float cn = fg * creg[r] + ig * gg;
                const float hn = og * tanhfast(cn);
                creg[r] = cn;
                stage_h[w][quad * 4 + r][n] = f2b(hn);
                if (lay) stage_o[w][quad * 4 + r][n] = hn;
                if (t == 511) {
                    const size_t o1 = (size_t)B_ * T_ * H_;   // 16,777,216
                    out[o1 +         (size_t)lay * 32768 + row * 512 + ug] = hn;
                    out[o1 + 65536 + (size_t)lay * 32768 + row * 512 + ug] = cn;
                }
            }
        }
        asm volatile("s_waitcnt lgkmcnt(0)" ::: "memory");  // stage visible within wave

        // transpose-store: lanes 0..31 write one u64 (4 units) each
        {
            const int row_id = lane >> 1;      // 0..15
            const int half   = lane & 1;
            if (lane < 32) {
                u64 hv = *(const u64*)&stage_h[w][row_id][half * 4];
                u16* hw = (lay ? h1ring : h0ring) + (t & 7) * 32768;
                const int off = (mrow0 + row_id) * 512 + ug8 * 8 + half * 4;
                __hip_atomic_store((u64*)(hw + off), hv, __ATOMIC_RELAXED, __HIP_MEMORY_SCOPE_AGENT);
                if (lay) {
                    float4 ov = *(const float4*)&stage_o[w][row_id][half * 4];
                    *(float4*)(out + ((size_t)(mrow0 + row_id) * T_ + t) * H_ + ug8 * 8 + half * 4) = ov;
                }
            }
        }

        // publish: drain stores to coherence point, then set our wave flag
        asm volatile("s_waitcnt vmcnt(0)" ::: "memory");
        if (lane == 0)
            __hip_atomic_store(myflag, t + 1, __ATOMIC_RELAXED, __HIP_MEMORY_SCOPE_AGENT);
    }
}

extern "C" void kernel_launch(void* const* d_in, const int* in_sizes, int n_in,
                              void* d_out, int out_size, void* d_ws, size_t ws_size,
                              hipStream_t stream) {
    const float* x   = (const float*)d_in[0];
    const float* h   = (const float*)d_in[1];
    const float* c   = (const float*)d_in[2];
    const float* Wx0 = (const float*)d_in[3];
    const float* Wh0 = (const float*)d_in[4];
    const float* b0  = (const float*)d_in[5];
    const float* Wx1 = (const float*)d_in[6];
    const float* Wh1 = (const float*)d_in[7];
    const float* b1  = (const float*)d_in[8];
    float* out = (float*)d_out;

    // ws layout (~34 MB): xb bf16, h rings (depth 8, bf16), flags.
    u16* xb     = (u16*)d_ws;                 // 16,777,216 u16
    u16* h0ring = xb + 16777216;              // 8*32768 u16
    u16* h1ring = h0ring + 262144;            // 8*32768 u16
    int* flags0 = (int*)(h1ring + 262144);    // 256 ints (32 blocks x 8 waves)
    int* flags1 = flags0 + 256;               // 256 ints

    k_init<<<8226, 256, 0, stream>>>(x, h, xb, h0ring, h1ring, flags0, flags1);
    k_lstm<<<NBLK, NTHR, 0, stream>>>(xb, Wx0, Wh0, b0, Wx1, Wh1, b1, c,
                                      h0ring, h1ring, flags0, flags1, out);
}

// Round 4
// 7905.817 us; speedup vs baseline: 1.8865x; 1.8865x over previous
//
#include <hip/hip_runtime.h>
#include <hip/hip_bf16.h>

// Sizes (fixed by the problem)
#define B_   64
#define T_   512
#define I_   512
#define H_   512
#define NBLK 128   // 64 blocks/layer; block owns 8 hidden units (32 gate cols)
#define NTHR 256   // 4 waves (1 wave/SIMD at 1 block/CU -> 512-reg budget for breg)

typedef short bf16x8 __attribute__((ext_vector_type(8)));
typedef float f32x4  __attribute__((ext_vector_type(4)));
typedef unsigned long long u64;
typedef unsigned short u16;

__device__ __forceinline__ u16 f2b(float f) {
    __hip_bfloat16 h = __float2bfloat16(f);   // RNE
    return __builtin_bit_cast(u16, h);
}

// Agent-scope (device-coherent, LLC-backed) 16B load from two u64 relaxed atomics.
// Bypasses the non-coherent per-XCD L2 -> no fences / cache maintenance needed.
__device__ __forceinline__ bf16x8 coh_ld8(const u16* p) {
    u64 lo = __hip_atomic_load((const u64*)p,     __ATOMIC_RELAXED, __HIP_MEMORY_SCOPE_AGENT);
    u64 hi = __hip_atomic_load((const u64*)p + 1, __ATOMIC_RELAXED, __HIP_MEMORY_SCOPE_AGENT);
    union { u64 q[2]; bf16x8 v; } u;
    u.q[0] = lo; u.q[1] = hi;
    return u.v;
}

// lane i checks the 4 wave-flags of block i (16B); true if all >= tgt. 256 flags.
__device__ __forceinline__ bool flags_ge(const int* f, int lane, int tgt) {
    const u64* p = (const u64*)(f + 4 * lane);
    u64 a = __hip_atomic_load(p,     __ATOMIC_RELAXED, __HIP_MEMORY_SCOPE_AGENT);
    u64 b = __hip_atomic_load(p + 1, __ATOMIC_RELAXED, __HIP_MEMORY_SCOPE_AGENT);
    int m0 = min((int)(unsigned)a, (int)(a >> 32));
    int m1 = min((int)(unsigned)b, (int)(b >> 32));
    return min(m0, m1) >= tgt;
}

__device__ __forceinline__ float sigm(float z)     { return 1.f / (1.f + __expf(-z)); }
__device__ __forceinline__ float tanhfast(float z) { return 1.f - 2.f / (__expf(2.f * z) + 1.f); }

// Init: x fp32 -> bf16, initial h -> ring slot 7 (both layers), flags = 0.
__global__ void k_init(const float* __restrict__ x, const float* __restrict__ h,
                       u16* __restrict__ xb, u16* __restrict__ h0ring, u16* __restrict__ h1ring,
                       int* __restrict__ flags0, int* __restrict__ flags1) {
    long i = (long)blockIdx.x * 256 + threadIdx.x;
    if (i < 2097152) {                          // x: 16,777,216 floats, 8 per thread
        const float* p = x + i * 8;
        float4 a = *(const float4*)p;
        float4 b = *(const float4*)(p + 4);
        union { u16 s[8]; bf16x8 v; } u;
        u.s[0]=f2b(a.x); u.s[1]=f2b(a.y); u.s[2]=f2b(a.z); u.s[3]=f2b(a.w);
        u.s[4]=f2b(b.x); u.s[5]=f2b(b.y); u.s[6]=f2b(b.z); u.s[7]=f2b(b.w);
        *(bf16x8*)(xb + i * 8) = u.v;
    } else if (i < 2097152 + 8192) {            // h: [2][64][512] = 65536 floats
        long j = i - 2097152;
        const float* p = h + j * 8;
        #pragma unroll
        for (int jj = 0; jj < 8; ++jj) {
            long idx = j * 8 + jj;
            u16 v = f2b(p[jj]);
            if (idx < 32768) h0ring[7 * 32768 + idx] = v;
            else             h1ring[7 * 32768 + (idx - 32768)] = v;
        }
    } else if (i < 2097152 + 8192 + 512) {      // flags
        int j = (int)(i - (2097152 + 8192));
        if (j < 256) flags0[j] = 0; else flags1[j - 256] = 0;
    }
}

// Repack weights (fp32, stride-2048 gather) -> bf16 in exact breg fragment order.
// wb index = ((((l*64 + ug8)*2 + ct)*32 + f)*64 + lane) * 8 elems.
__global__ void k_packw(const float* __restrict__ Wx0, const float* __restrict__ Wh0,
                        const float* __restrict__ Wx1, const float* __restrict__ Wh1,
                        u16* __restrict__ wb) {
    const int idx  = blockIdx.x * 256 + threadIdx.x;   // 524288 total
    const int lane = idx & 63;
    const int f    = (idx >> 6) & 31;
    const int ct   = (idx >> 11) & 1;
    const int ug8  = (idx >> 12) & 63;
    const int l    = idx >> 18;
    const float* Wx = l ? Wx1 : Wx0;
    const float* Wh = l ? Wh1 : Wh0;
    const int n    = lane & 15;
    const int quad = lane >> 4;
    const int c    = ct * 16 + n;
    const int gcol = (c >> 3) * 512 + ug8 * 8 + (c & 7);
    union { u16 s[8]; bf16x8 v; } u;
    #pragma unroll
    for (int j = 0; j < 8; ++j) {
        const int k = f * 32 + quad * 8 + j;
        const float v = (k < 512) ? Wx[(size_t)k * 2048 + gcol]
                                  : Wh[(size_t)(k - 512) * 2048 + gcol];
        u.s[j] = f2b(v);
    }
    *(bf16x8*)(wb + (size_t)idx * 8) = u.v;
}

__global__ __launch_bounds__(NTHR, 1) void k_lstm(
    const u16* __restrict__ xb, const u16* __restrict__ wb,
    const float* __restrict__ b0, const float* __restrict__ b1,
    const float* __restrict__ c_in,
    u16* __restrict__ h0ring, u16* __restrict__ h1ring,
    int* __restrict__ flags0, int* __restrict__ flags1,
    float* __restrict__ out)
{
    __shared__ u16   stage_h[4][16][8];   // per wave: 16 rows x 8 units (bf16)
    __shared__ float stage_o[4][16][8];   // per wave: 16 rows x 8 units (fp32, layer1 out)

    const int tid  = threadIdx.x;
    const int bid  = blockIdx.x;
    const int lay  = bid >> 6;          // 0 or 1
    const int ub   = bid & 63;          // block owns units [ub*8, ub*8+8)
    const int w    = tid >> 6;          // wave 0..3 = M-tile
    const int lane = tid & 63;
    const int n    = lane & 15;
    const int quad = lane >> 4;
    const int ug8  = ub;                // 8-unit group

    const float* bb = lay ? b1 : b0;
    const float bi = bb[0] + bb[1];
    const float bf = bb[2] + bb[3];
    const float bg = bb[4] + bb[5];
    const float bo = bb[6] + bb[7];

    // ---- Preload weight B-fragments from the packed array (coalesced). ----
    bf16x8 breg[2][32];
    {
        const u16* wsrc = wb + ((size_t)(lay * 64 + ug8)) * 32768;  // 2*32*64*8 u16 per (l,ug8)
        #pragma unroll
        for (int ct = 0; ct < 2; ++ct)
            #pragma unroll
            for (int f = 0; f < 32; ++f)
                breg[ct][f] = *(const bf16x8*)(wsrc + (((ct * 32 + f) * 64) + lane) * 8);
    }

    const int mrow0 = w * 16;
    const int arow  = mrow0 + n;            // A row this lane supplies
    int* myflag = (lay ? flags1 : flags0) + ub * 4 + w;

    // c-state in registers: lanes n<8 own rows mrow0+quad*4+r, unit ug8*8+n
    float creg[4];
    if (n < 8) {
        const int ug = ug8 * 8 + n;
        #pragma unroll
        for (int r = 0; r < 4; ++r)
            creg[r] = c_in[(size_t)lay * 32768 + (mrow0 + quad * 4 + r) * 512 + ug];
    }

    for (int t = 0; t < 512; ++t) {
        f32x4 acc0 = {0.f, 0.f, 0.f, 0.f};
        f32x4 acc1 = {0.f, 0.f, 0.f, 0.f};

        if (lay == 0) {
            // x part first: independent of h -> off the critical path
            const u16* px = xb + ((size_t)arow * T_ + t) * I_;
            bf16x8 xa[16];
            #pragma unroll
            for (int f = 0; f < 16; ++f)
                xa[f] = *(const bf16x8*)(px + f * 32 + quad * 8);
            #pragma unroll
            for (int f = 0; f < 16; ++f) {
                acc0 = __builtin_amdgcn_mfma_f32_16x16x32_bf16(xa[f], breg[0][f], acc0, 0, 0, 0);
                acc1 = __builtin_amdgcn_mfma_f32_16x16x32_bf16(xa[f], breg[1][f], acc1, 0, 0, 0);
            }

            // wait: peers done t-1 (h0[t-1] ready); layer1 done t-7 (ring WAR)
            while (!__all(flags_ge(flags0, lane, t) && flags_ge(flags1, lane, t - 6)))
                __builtin_amdgcn_s_sleep(1);
            asm volatile("" ::: "memory");

            const u16* ph = h0ring + ((t - 1) & 7) * 32768 + arow * H_;
            bf16x8 ha[16];
            #pragma unroll
            for (int f = 0; f < 16; ++f)
                ha[f] = coh_ld8(ph + f * 32 + quad * 8);
            #pragma unroll
            for (int f = 0; f < 16; ++f) {
                acc0 = __builtin_amdgcn_mfma_f32_16x16x32_bf16(ha[f], breg[0][16 + f], acc0, 0, 0, 0);
                acc1 = __builtin_amdgcn_mfma_f32_16x16x32_bf16(ha[f], breg[1][16 + f], acc1, 0, 0, 0);
            }
        } else {
            // phase 1: own-layer h1[t-1]
            while (!__all(flags_ge(flags1, lane, t)))
                __builtin_amdgcn_s_sleep(1);
            asm volatile("" ::: "memory");
            const u16* p1 = h1ring + ((t - 1) & 7) * 32768 + arow * H_;
            bf16x8 ha1[16];
            #pragma unroll
            for (int f = 0; f < 16; ++f)
                ha1[f] = coh_ld8(p1 + f * 32 + quad * 8);

            // phase 2 poll overlaps the ha1 load flight
            while (!__all(flags_ge(flags0, lane, t + 1)))
                __builtin_amdgcn_s_sleep(1);
            asm volatile("" ::: "memory");

            #pragma unroll
            for (int f = 0; f < 16; ++f) {
                acc0 = __builtin_amdgcn_mfma_f32_16x16x32_bf16(ha1[f], breg[0][16 + f], acc0, 0, 0, 0);
                acc1 = __builtin_amdgcn_mfma_f32_16x16x32_bf16(ha1[f], breg[1][16 + f], acc1, 0, 0, 0);
            }
            const u16* p0 = h0ring + (t & 7) * 32768 + arow * H_;
            bf16x8 ha0[16];
            #pragma unroll
            for (int f = 0; f < 16; ++f)
                ha0[f] = coh_ld8(p0 + f * 32 + quad * 8);
            #pragma unroll
            for (int f = 0; f < 16; ++f) {
                acc0 = __builtin_amdgcn_mfma_f32_16x16x32_bf16(ha0[f], breg[0][f], acc0, 0, 0, 0);
                acc1 = __builtin_amdgcn_mfma_f32_16x16x32_bf16(ha0[f], breg[1][f], acc1, 0, 0, 0);
            }
        }

        // D layout: col = lane&15, row = quad*4 + reg.
        // acc0 cols: n<8 -> gate i (unit n), n>=8 -> gate f (unit n-8)
        // acc1 cols: n<8 -> gate g,          n>=8 -> gate o
        f32x4 s0, s1;
        #pragma unroll
        for (int r = 0; r < 4; ++r) {
            s0[r] = __shfl_xor(acc0[r], 8);   // lane n gets zf
            s1[r] = __shfl_xor(acc1[r], 8);   // lane n gets zo
        }
        float hfin[4], cfin[4];               // for t==511 finals (stored after flag)
        if (n < 8) {
            #pragma unroll
            for (int r = 0; r < 4; ++r) {
                const float zi = acc0[r] + bi;
                const float zf = s0[r]   + bf;
                const float zg = acc1[r] + bg;
                const float zo = s1[r]   + bo;
                const float ig = sigm(zi);
                const float fg = sigm(zf);
                const float gg = tanhfast(zg);
                const float og = sigm(zo);
                const float cn = fg * creg[r] + ig * gg;
                const float hn = og * tanhfast(cn);
                creg[r] = cn;
                hfin[r] = hn; cfin[r] = cn;
                stage_h[w][quad * 4 + r][n] = f2b(hn);
                if (lay) stage_o[w][quad * 4 + r][n] = hn;
            }
        }
        asm volatile("s_waitcnt lgkmcnt(0)" ::: "memory");  // stage visible within wave

        // transpose-store: lanes 0..31 emit one coalesced u64 (4 units) each
        const int row_id = lane >> 1;      // 0..15
        const int half   = lane & 1;
        if (lane < 32) {
            u64 hv = *(const u64*)&stage_h[w][row_id][half * 4];
            u16* hw = (lay ? h1ring : h0ring) + (t & 7) * 32768;
            const int off = (mrow0 + row_id) * 512 + ug8 * 8 + half * 4;
            __hip_atomic_store((u64*)(hw + off), hv, __ATOMIC_RELAXED, __HIP_MEMORY_SCOPE_AGENT);
        }

        // publish: drain the h store, then set our wave flag
        asm volatile("s_waitcnt vmcnt(0)" ::: "memory");
        if (lane == 0)
            __hip_atomic_store(myflag, t + 1, __ATOMIC_RELAXED, __HIP_MEMORY_SCOPE_AGENT);

        // out / final-state stores AFTER the flag (not on the sync critical path)
        if (lay && lane < 32) {
            float4 ov = *(const float4*)&stage_o[w][row_id][half * 4];
            *(float4*)(out + ((size_t)(mrow0 + row_id) * T_ + t) * H_ + ug8 * 8 + half * 4) = ov;
        }
        if (t == 511 && n < 8) {
            const int ug = ug8 * 8 + n;
            const size_t o1 = (size_t)B_ * T_ * H_;   // 16,777,216
            #pragma unroll
            for (int r = 0; r < 4; ++r) {
                const int row = mrow0 + quad * 4 + r;
                out[o1 +         (size_t)lay * 32768 + row * 512 + ug] = hfin[r];
                out[o1 + 65536 + (size_t)lay * 32768 + row * 512 + ug] = cfin[r];
            }
        }
    }
}

extern "C" void kernel_launch(void* const* d_in, const int* in_sizes, int n_in,
                              void* d_out, int out_size, void* d_ws, size_t ws_size,
                              hipStream_t stream) {
    const float* x   = (const float*)d_in[0];
    const float* h   = (const float*)d_in[1];
    const float* c   = (const float*)d_in[2];
    const float* Wx0 = (const float*)d_in[3];
    const float* Wh0 = (const float*)d_in[4];
    const float* b0  = (const float*)d_in[5];
    const float* Wx1 = (const float*)d_in[6];
    const float* Wh1 = (const float*)d_in[7];
    const float* b1  = (const float*)d_in[8];
    float* out = (float*)d_out;

    // ws layout (~43 MB): xb bf16, h rings (depth 8), flags, packed weights.
    u16* xb     = (u16*)d_ws;                 // 16,777,216 u16
    u16* h0ring = xb + 16777216;              // 8*32768 u16
    u16* h1ring = h0ring + 262144;            // 8*32768 u16
    int* flags0 = (int*)(h1ring + 262144);    // 256 ints (64 blocks x 4 waves)
    int* flags1 = flags0 + 256;               // 256 ints
    u16* wbp    = (u16*)(flags1 + 256);       // 4,194,304 u16 (2 x 64 x 32768)

    k_init <<<8226, 256, 0, stream>>>(x, h, xb, h0ring, h1ring, flags0, flags1);
    k_packw<<<2048, 256, 0, stream>>>(Wx0, Wh0, Wx1, Wh1, wbp);
    k_lstm <<<NBLK, NTHR, 0, stream>>>(xb, wbp, b0, b1, c,
                                       h0ring, h1ring, flags0, flags1, out);
}